// Round 1
// baseline (9856.292 us; speedup 1.0000x reference)
//
#include <hip/hip_runtime.h>
#include <hip/hip_bf16.h>
#include <math.h>

// ---------------------------------------------------------------------------
// sMLP4: 50-step spiking MLP. Correctness-first fp64 implementation.
//   - threefry2x32 (JAX partitionable mode) bit-exact spike generation
//   - binary-spike x fp32-weight products are exact; accumulate fp64
//   - spikes bit-packed in u64 words; __ballot (wave=64) produces them
// ---------------------------------------------------------------------------

#define NSTEPS 50
#define BATCH  1024
#define NIN    784      // padded to 832 rows (13*64) in W1T
#define NH     1000     // padded to 1024 cols in W1T / rows in W2T
#define NOUT   100      // padded to 128 cols in W2T

// workspace layout (bytes)
#define OFF_SPK   0u               // u64[50*1024*16]          = 6,553,600
#define OFF_W1T   6553600u         // f32[832*1024]            = 3,407,872
#define OFF_W2T   9961472u         // f32[1024*128]            =   524,288
#define OFF_H1M   10485760u        // f64[1024*1024]           = 8,388,608
#define OFF_H1S   18874368u        // u64[1024*16]             =   131,072
#define OFF_H2M   19005440u        // f64[1024*128]            = 1,048,576
#define OFF_H2S   20054016u        // u64[1024*2]              =    16,384
#define OFF_ACC   20070400u        // f64[1024*16]             =   131,072
// total 20,201,472 bytes

// ---------------------------------------------------------------------------
// threefry2x32, key = (0, 42)  [jax.random.key(42)]
// partitionable mode, 32-bit draw: block counter (hi=0, lo=i), bits = x0^x1
// ---------------------------------------------------------------------------
__device__ __forceinline__ unsigned int rotl32(unsigned int v, int d) {
  return (v << d) | (v >> (32 - d));
}

__device__ __forceinline__ unsigned int tf_bits(unsigned int i) {
  const unsigned int ks0 = 0u;
  const unsigned int ks1 = 42u;
  const unsigned int ks2 = 0x1BD11BDAu ^ 0u ^ 42u;
  unsigned int x0 = 0u + ks0;     // counts_hi == 0 for size < 2^32
  unsigned int x1 = i + ks1;
#define TF_RND(r) { x0 += x1; x1 = rotl32(x1, r); x1 ^= x0; }
  TF_RND(13) TF_RND(15) TF_RND(26) TF_RND(6)
  x0 += ks1; x1 += ks2 + 1u;
  TF_RND(17) TF_RND(29) TF_RND(16) TF_RND(24)
  x0 += ks2; x1 += ks0 + 2u;
  TF_RND(13) TF_RND(15) TF_RND(26) TF_RND(6)
  x0 += ks0; x1 += ks1 + 3u;
  TF_RND(17) TF_RND(29) TF_RND(16) TF_RND(24)
  x0 += ks1; x1 += ks2 + 4u;
  TF_RND(13) TF_RND(15) TF_RND(26) TF_RND(6)
  x0 += ks2; x1 += ks0 + 5u;
#undef TF_RND
  return x0 ^ x1;
}

// ---------------------------------------------------------------------------
// prep: transpose + zero-pad weights.
// W1 (1000,784) -> W1T[j*1024 + o], j<832, o<1024
// W2 (100,1000) -> W2T[j*128  + o], j<1024, o<128
// ---------------------------------------------------------------------------
__global__ __launch_bounds__(256) void prep_kernel(
    const float* __restrict__ W1, const float* __restrict__ W2,
    float* __restrict__ W1T, float* __restrict__ W2T) {
  int idx = blockIdx.x * 256 + threadIdx.x;
  const int NW1 = 832 * 1024;
  const int NW2 = 1024 * 128;
  if (idx < NW1) {
    int j = idx >> 10;          // 0..831
    int o = idx & 1023;         // 0..1023
    W1T[idx] = (j < NIN && o < NH) ? W1[o * NIN + j] : 0.0f;
  } else if (idx < NW1 + NW2) {
    int k = idx - NW1;
    int j = k >> 7;             // 0..1023
    int o = k & 127;            // 0..127
    W2T[k] = (j < NH && o < NOUT) ? W2[o * NH + j] : 0.0f;
  }
}

// ---------------------------------------------------------------------------
// init: membranes = 0.5, spikes = 0, acc = 0
// ---------------------------------------------------------------------------
__global__ __launch_bounds__(256) void init_kernel(
    double* __restrict__ h1m, double* __restrict__ h2m,
    unsigned long long* __restrict__ h1s, unsigned long long* __restrict__ h2s,
    double* __restrict__ acc) {
  int idx = blockIdx.x * 256 + threadIdx.x;
  if (idx < 1024 * 1024) h1m[idx] = 0.5;
  if (idx < 1024 * 128)  h2m[idx] = 0.5;
  if (idx < 1024 * 16)   { h1s[idx] = 0ull; acc[idx] = 0.0; }
  if (idx < 1024 * 2)    h2s[idx] = 0ull;
}

// ---------------------------------------------------------------------------
// spikegen: one block per (t,b) row; 13 u64 words of 784 spike bits
// u.flat index = row*784 + j ; spike = (u < x[b,j])
// ---------------------------------------------------------------------------
__global__ __launch_bounds__(256) void spikegen_kernel(
    const float* __restrict__ x, unsigned long long* __restrict__ spk) {
  int row  = blockIdx.x;        // t*1024 + b
  int b    = row & 1023;
  int tid  = threadIdx.x;
  int lane = tid & 63;
  int wave = tid >> 6;
  for (int it = 0; it < 4; ++it) {
    int chunk = it * 4 + wave;        // uniform within wave
    if (chunk > 12) continue;
    int j = chunk * 64 + lane;
    bool spike = false;
    if (j < NIN) {
      unsigned int i = (unsigned int)row * 784u + (unsigned int)j;
      unsigned int bits = tf_bits(i);
      float u = __uint_as_float((bits >> 9) | 0x3f800000u) - 1.0f;
      spike = u < x[b * NIN + j];
    }
    unsigned long long m = __ballot(spike);
    if (lane == 0) spk[(size_t)row * 16 + chunk] = m;
  }
}

// ---------------------------------------------------------------------------
// layer1: grid (8 o-blocks of 128, 64 b-blocks of 16), 256 threads.
// thread: o0 = ob*128+lane, o1 = o0+64 ; 4 b rows per thread (wave*4+i).
// h1m = h1m*decay*(1-h1s_old) + spk@W1T ; h1s_new = (h1m-1 >= 0)
// ---------------------------------------------------------------------------
__global__ __launch_bounds__(256) void layer1_kernel(
    const float* __restrict__ W1T, const unsigned long long* __restrict__ spk,
    double* __restrict__ h1m, unsigned long long* __restrict__ h1s,
    const float* __restrict__ tau0, int t) {
  __shared__ float wt[64 * 128];
  __shared__ unsigned long long sb[16];
  int tid  = threadIdx.x;
  int lane = tid & 63;
  int wave = tid >> 6;
  int ob = blockIdx.x;            // 0..7
  int bb = blockIdx.y;            // 0..63

  double a0[4] = {0.0, 0.0, 0.0, 0.0};
  double a1[4] = {0.0, 0.0, 0.0, 0.0};

  for (int c = 0; c < 13; ++c) {
    const float* src = W1T + (size_t)(c * 64) * 1024 + ob * 128;
    int jrow = tid >> 5;          // 0..7
    int c4   = (tid & 31) * 4;
#pragma unroll
    for (int r = 0; r < 8; ++r) {
      int jj = r * 8 + jrow;
      *(float4*)&wt[jj * 128 + c4] = *(const float4*)&src[(size_t)jj * 1024 + c4];
    }
    if (tid < 16) sb[tid] = spk[(size_t)(t * 1024 + bb * 16 + tid) * 16 + c];
    __syncthreads();

    unsigned long long s0 = sb[wave * 4 + 0];
    unsigned long long s1 = sb[wave * 4 + 1];
    unsigned long long s2 = sb[wave * 4 + 2];
    unsigned long long s3 = sb[wave * 4 + 3];
#pragma unroll 4
    for (int jj = 0; jj < 64; ++jj) {
      double w0 = (double)wt[jj * 128 + lane];
      double w1 = (double)wt[jj * 128 + 64 + lane];
      bool b0 = (s0 >> jj) & 1; bool b1 = (s1 >> jj) & 1;
      bool b2 = (s2 >> jj) & 1; bool b3 = (s3 >> jj) & 1;
      a0[0] += b0 ? w0 : 0.0;  a1[0] += b0 ? w1 : 0.0;
      a0[1] += b1 ? w0 : 0.0;  a1[1] += b1 ? w1 : 0.0;
      a0[2] += b2 ? w0 : 0.0;  a1[2] += b2 ? w1 : 0.0;
      a0[3] += b3 ? w0 : 0.0;  a1[3] += b3 ? w1 : 0.0;
    }
    __syncthreads();
  }

  double decay = 1.0 / (1.0 + exp(-(double)tau0[0]));
  int o0 = ob * 128 + lane;
  int o1 = o0 + 64;
#pragma unroll
  for (int i = 0; i < 4; ++i) {
    int b = bb * 16 + wave * 4 + i;
    unsigned long long ow0 = h1s[b * 16 + ob * 2];
    unsigned long long ow1 = h1s[b * 16 + ob * 2 + 1];
    double so0 = ((ow0 >> lane) & 1) ? 1.0 : 0.0;
    double so1 = ((ow1 >> lane) & 1) ? 1.0 : 0.0;
    double m0 = h1m[(size_t)b * 1024 + o0];
    double m1 = h1m[(size_t)b * 1024 + o1];
    m0 = m0 * decay * (1.0 - so0) + a0[i];
    m1 = m1 * decay * (1.0 - so1) + a1[i];
    bool n0 = (m0 - 1.0) >= 0.0;
    bool n1 = ((m1 - 1.0) >= 0.0) && (o1 < NH);
    h1m[(size_t)b * 1024 + o0] = m0;
    h1m[(size_t)b * 1024 + o1] = m1;
    unsigned long long nm0 = __ballot(n0);
    unsigned long long nm1 = __ballot(n1);
    if (lane == 0) {
      h1s[b * 16 + ob * 2]     = nm0;
      h1s[b * 16 + ob * 2 + 1] = nm1;
    }
  }
}

// ---------------------------------------------------------------------------
// layer2 + pool + accumulator: grid 128 blocks of 8 b rows; block owns all
// 100 outputs for its rows. K = 1024 (padded; h1s bits >=1000 are 0).
// ---------------------------------------------------------------------------
__global__ __launch_bounds__(256) void layer2_kernel(
    const float* __restrict__ W2T, const unsigned long long* __restrict__ h1s,
    double* __restrict__ h2m, unsigned long long* __restrict__ h2s,
    double* __restrict__ acc,
    const float* __restrict__ tauv, const float* __restrict__ acct,
    int t, float* __restrict__ out) {
  __shared__ float wt[64 * 128];
  __shared__ unsigned long long sb[8];
  __shared__ float sp[8][104];
  int tid  = threadIdx.x;
  int lane = tid & 63;
  int wave = tid >> 6;
  int bb = blockIdx.x;            // 0..127

  double a0[2] = {0.0, 0.0};
  double a1[2] = {0.0, 0.0};

  for (int c = 0; c < 16; ++c) {
    const float* src = W2T + (size_t)(c * 64) * 128;
    int jrow = tid >> 5;
    int c4   = (tid & 31) * 4;
#pragma unroll
    for (int r = 0; r < 8; ++r) {
      int jj = r * 8 + jrow;
      *(float4*)&wt[jj * 128 + c4] = *(const float4*)&src[jj * 128 + c4];
    }
    if (tid < 8) sb[tid] = h1s[(bb * 8 + tid) * 16 + c];
    __syncthreads();

    unsigned long long s0 = sb[wave * 2 + 0];
    unsigned long long s1 = sb[wave * 2 + 1];
#pragma unroll 4
    for (int jj = 0; jj < 64; ++jj) {
      double w0 = (double)wt[jj * 128 + lane];
      double w1 = (double)wt[jj * 128 + 64 + lane];
      bool b0 = (s0 >> jj) & 1; bool b1 = (s1 >> jj) & 1;
      a0[0] += b0 ? w0 : 0.0;  a1[0] += b0 ? w1 : 0.0;
      a0[1] += b1 ? w0 : 0.0;  a1[1] += b1 ? w1 : 0.0;
    }
    __syncthreads();
  }

  double decayv = 1.0 / (1.0 + exp(-(double)tauv[0]));
  double accdec = 1.0 / (1.0 + exp(-(double)acct[0]));
  int o0 = lane;
  int o1 = lane + 64;
#pragma unroll
  for (int i = 0; i < 2; ++i) {
    int b = bb * 8 + wave * 2 + i;
    unsigned long long ow0 = h2s[b * 2];
    unsigned long long ow1 = h2s[b * 2 + 1];
    double so0 = ((ow0 >> lane) & 1) ? 1.0 : 0.0;
    double so1 = ((ow1 >> lane) & 1) ? 1.0 : 0.0;
    double m0 = h2m[(size_t)b * 128 + o0];
    double m1 = h2m[(size_t)b * 128 + o1];
    m0 = m0 * decayv * (1.0 - so0) + a0[i];
    m1 = m1 * decayv * (1.0 - so1) + a1[i];
    bool n0 = (m0 - 1.0) >= 0.0;
    bool n1 = ((m1 - 1.0) >= 0.0) && (o1 < NOUT);
    h2m[(size_t)b * 128 + o0] = m0;
    h2m[(size_t)b * 128 + o1] = m1;
    unsigned long long nm0 = __ballot(n0);
    unsigned long long nm1 = __ballot(n1);
    if (lane == 0) {
      h2s[b * 2]     = nm0;
      h2s[b * 2 + 1] = nm1;
    }
    int bl = wave * 2 + i;
    sp[bl][o0] = n0 ? 1.0f : 0.0f;
    if (o1 < 104) sp[bl][o1] = n1 ? 1.0f : 0.0f;
  }
  __syncthreads();

  // pooling + accumulator: 8 rows x 10 groups = 80 tasks
  if (tid < 80) {
    int bl = tid / 10;
    int g  = tid % 10;
    double sum = 0.0;
#pragma unroll
    for (int k = 0; k < 10; ++k) sum += (double)sp[bl][g * 10 + k];
    double boost = sum / 10.0;
    int b = bb * 8 + bl;
    double a = acc[b * 16 + g];
    a = a * accdec + boost;
    acc[b * 16 + g] = a;
    if (t == NSTEPS - 1) out[b * 10 + g] = (float)a;
  }
}

// ---------------------------------------------------------------------------
extern "C" void kernel_launch(void* const* d_in, const int* in_sizes, int n_in,
                              void* d_out, int out_size, void* d_ws, size_t ws_size,
                              hipStream_t stream) {
  const float* x    = (const float*)d_in[0];
  const float* W1   = (const float*)d_in[1];
  const float* W2   = (const float*)d_in[2];
  const float* tau0 = (const float*)d_in[3];
  const float* tauv = (const float*)d_in[4];
  const float* acct = (const float*)d_in[5];
  float* out = (float*)d_out;
  char*  ws  = (char*)d_ws;

  unsigned long long* spk = (unsigned long long*)(ws + OFF_SPK);
  float*  W1T = (float*)(ws + OFF_W1T);
  float*  W2T = (float*)(ws + OFF_W2T);
  double* h1m = (double*)(ws + OFF_H1M);
  unsigned long long* h1s = (unsigned long long*)(ws + OFF_H1S);
  double* h2m = (double*)(ws + OFF_H2M);
  unsigned long long* h2s = (unsigned long long*)(ws + OFF_H2S);
  double* acc = (double*)(ws + OFF_ACC);

  prep_kernel<<<(832 * 1024 + 1024 * 128 + 255) / 256, 256, 0, stream>>>(W1, W2, W1T, W2T);
  init_kernel<<<(1024 * 1024 + 255) / 256, 256, 0, stream>>>(h1m, h2m, h1s, h2s, acc);
  spikegen_kernel<<<NSTEPS * BATCH, 256, 0, stream>>>(x, spk);

  for (int t = 0; t < NSTEPS; ++t) {
    layer1_kernel<<<dim3(8, 64), 256, 0, stream>>>(W1T, spk, h1m, h1s, tau0, t);
    layer2_kernel<<<128, 256, 0, stream>>>(W2T, h1s, h2m, h2s, acc, tauv, acct, t, out);
  }
}

// Round 2
// 2070.516 us; speedup vs baseline: 4.7603x; 4.7603x over previous
//
#include <hip/hip_runtime.h>
#include <hip/hip_bf16.h>
#include <math.h>

// ---------------------------------------------------------------------------
// sMLP4 via exact int8-sliced MFMA.
//   w (fp32, |w|<0.25, ulp>=2^-48)  ==  sum_s d_s * 256^s * 2^-48, d_s in i8.
//   spike in {0,1}  ->  per-slice dot is exact int32 via v_mfma_i32_32x32x32_i8
//   T = Horner(d-slices) int64 (exact), I = (double)T * 2^-48 (exact).
//   Membrane recurrence identical (fp64) -> bit-identical trajectory to the
//   passing round-1 kernel.
// ---------------------------------------------------------------------------

#define NSTEPS 50

typedef __attribute__((ext_vector_type(4)))  int i32x4;
typedef __attribute__((ext_vector_type(16))) int i32x16;

// workspace layout (bytes)
#define OFF_AFRAG 0ull           // i8 [50*32mt*26kc][64lane*16] = 42,598,400
#define OFF_BF1   42598400ull    // i8 [6s*32nt*26kc][1024]      =  5,111,808
#define OFF_BF2   47710208ull    // i8 [6s*4nt*32kc][1024]       =    786,432
#define OFF_H1M   48496640ull    // f64[1024*1024]               =  8,388,608
#define OFF_H1SB  56885248ull    // i8 [1024*1024]  (== layer2 A)=  1,048,576
#define OFF_H2M   57933824ull    // f64[1024*128]                =  1,048,576
#define OFF_H2SB  58982400ull    // i8 [1024*128]                =    131,072
#define OFF_ACC   59113472ull    // f64[1024*16]                 =    131,072
// total 59,244,544 bytes

// ---------------------------------------------------------------------------
// threefry2x32, key (0,42), partitionable mode: bits(i) = x0^x1 on ctr (0,i)
// ---------------------------------------------------------------------------
__device__ __forceinline__ unsigned int rotl32(unsigned int v, int d) {
  return (v << d) | (v >> (32 - d));
}

__device__ __forceinline__ unsigned int tf_bits(unsigned int i) {
  const unsigned int ks0 = 0u;
  const unsigned int ks1 = 42u;
  const unsigned int ks2 = 0x1BD11BDAu ^ 0u ^ 42u;
  unsigned int x0 = 0u + ks0;
  unsigned int x1 = i + ks1;
#define TF_RND(r) { x0 += x1; x1 = rotl32(x1, r); x1 ^= x0; }
  TF_RND(13) TF_RND(15) TF_RND(26) TF_RND(6)
  x0 += ks1; x1 += ks2 + 1u;
  TF_RND(17) TF_RND(29) TF_RND(16) TF_RND(24)
  x0 += ks2; x1 += ks0 + 2u;
  TF_RND(13) TF_RND(15) TF_RND(26) TF_RND(6)
  x0 += ks0; x1 += ks1 + 3u;
  TF_RND(17) TF_RND(29) TF_RND(16) TF_RND(24)
  x0 += ks1; x1 += ks2 + 4u;
  TF_RND(13) TF_RND(15) TF_RND(26) TF_RND(6)
  x0 += ks2; x1 += ks0 + 5u;
#undef TF_RND
  return x0 ^ x1;
}

// ---------------------------------------------------------------------------
// prep: fp32 weights -> 6 signed base-256 digit slices, stored in the exact
// per-lane fragment order the GEMM waves load (fully coalesced dwordx4).
// B-frag mapping (32x32x32 i8): lane holds B[k = kc*32+(lane>>5)*16+jj][n]
// with n = nt*32 + (lane&31).
// ---------------------------------------------------------------------------
__global__ __launch_bounds__(256) void prep_kernel(
    const float* __restrict__ W1, const float* __restrict__ W2,
    signed char* __restrict__ B1, signed char* __restrict__ B2) {
  int idx = blockIdx.x * 256 + threadIdx.x;
  const int NB1 = 6 * 32 * 26 * 1024;   // 5,111,808
  const int NB2 = 6 * 4 * 32 * 1024;    //   786,432
  float w;
  int s;
  signed char* dst;
  if (idx < NB1) {
    int jj = idx & 15;
    int lane = (idx >> 4) & 63;
    int kc = (idx >> 10) % 26;
    int rest = (idx >> 10) / 26;
    int nt = rest & 31;
    s = rest >> 5;
    int k = kc * 32 + ((lane >> 5) << 4) + jj;   // input index (<832)
    int o = nt * 32 + (lane & 31);               // output index (<1024)
    w = (o < 1000 && k < 784) ? W1[o * 784 + k] : 0.0f;
    dst = B1 + idx;
  } else if (idx < NB1 + NB2) {
    int m = idx - NB1;
    int jj = m & 15;
    int lane = (m >> 4) & 63;
    int kc = (m >> 10) & 31;
    int rest = (m >> 10) >> 5;
    int nt = rest & 3;
    s = rest >> 2;
    int k = kc * 32 + ((lane >> 5) << 4) + jj;   // h1 index (<1024)
    int o = nt * 32 + (lane & 31);               // output index (<128)
    w = (o < 100 && k < 1000) ? W2[o * 1000 + k] : 0.0f;
    dst = B2 + m;
  } else {
    return;
  }
  long long V = llrint((double)w * 281474976710656.0);  // w * 2^48, exact
  signed char d = 0;
  for (int q = 0; q <= s; ++q) {
    d = (signed char)(V & 0xFF);
    V = (V - (long long)d) >> 8;
  }
  *dst = d;
}

// ---------------------------------------------------------------------------
// init: membranes 0.5, spikes 0, acc 0
// ---------------------------------------------------------------------------
__global__ __launch_bounds__(256) void init_kernel(
    double* __restrict__ h1m, double* __restrict__ h2m,
    int* __restrict__ h1sb, int* __restrict__ h2sb,
    double* __restrict__ accum) {
  int idx = blockIdx.x * 256 + threadIdx.x;
  if (idx < 1024 * 1024) h1m[idx] = 0.5;
  if (idx < 1024 * 128)  h2m[idx] = 0.5;
  if (idx < 262144)      h1sb[idx] = 0;
  if (idx < 32768)       h2sb[idx] = 0;
  if (idx < 16384)       accum[idx] = 0.0;
}

// ---------------------------------------------------------------------------
// spikegen: spike bytes directly in layer1 A-fragment order.
// A-frag: lane holds A[m = mt*32+(lane&31)][k = kc*32+(lane>>5)*16+jj]
// one wave per (t, mt, kc) group; 16 bytes/lane packed into i32x4.
// ---------------------------------------------------------------------------
__global__ __launch_bounds__(256) void spikegen_kernel(
    const float* __restrict__ x, i32x4* __restrict__ A) {
  int g = blockIdx.x * 4 + (threadIdx.x >> 6);   // (t*32+mt)*26+kc
  int lane = threadIdx.x & 63;
  int kc = g % 26;
  int r = g / 26;
  int mt = r & 31;
  int t = r >> 5;
  int b = mt * 32 + (lane & 31);
  int j0 = kc * 32 + ((lane >> 5) << 4);
  unsigned int wds[4] = {0u, 0u, 0u, 0u};
#pragma unroll
  for (int jj = 0; jj < 16; ++jj) {
    int j = j0 + jj;
    if (j < 784) {
      unsigned int i = (unsigned int)(t * 1024 + b) * 784u + (unsigned int)j;
      unsigned int bits = tf_bits(i);
      float u = __uint_as_float((bits >> 9) | 0x3f800000u) - 1.0f;
      if (u < x[b * 784 + j]) wds[jj >> 2] |= 1u << (8 * (jj & 3));
    }
  }
  i32x4 v;
  v.x = (int)wds[0]; v.y = (int)wds[1]; v.z = (int)wds[2]; v.w = (int)wds[3];
  A[(size_t)g * 64 + lane] = v;
}

// ---------------------------------------------------------------------------
// layer1: grid (8 n-blocks, 32 m-tiles) x 256. Each wave: one 32x32 C tile,
// 6 slice accumulators, 26 K-chunks of v_mfma_i32_32x32x32_i8, pipelined.
// Epilogue: exact fp64 membrane + spike byte out (row-major = layer2 A-frag).
// ---------------------------------------------------------------------------
__global__ __launch_bounds__(256) void layer1_kernel(
    const signed char* __restrict__ Bf, const signed char* __restrict__ Af,
    double* __restrict__ h1m, signed char* __restrict__ h1sb,
    const float* __restrict__ tau0, int t) {
  int lane = threadIdx.x & 63;
  int wv = threadIdx.x >> 6;
  int mt = blockIdx.y;              // 0..31
  int nt = blockIdx.x * 4 + wv;     // 0..31

  const i32x4* Ap = (const i32x4*)Af + (size_t)(t * 32 + mt) * 26 * 64 + lane;
  const i32x4* Bp[6];
#pragma unroll
  for (int s = 0; s < 6; ++s)
    Bp[s] = (const i32x4*)Bf + (size_t)(s * 32 + nt) * 26 * 64 + lane;

  i32x16 C[6];
#pragma unroll
  for (int s = 0; s < 6; ++s)
#pragma unroll
    for (int i = 0; i < 16; ++i) C[s][i] = 0;

  i32x4 a = Ap[0];
  i32x4 b[6];
#pragma unroll
  for (int s = 0; s < 6; ++s) b[s] = Bp[s][0];

  for (int kc = 0; kc < 26; ++kc) {
    i32x4 an;
    i32x4 bn[6];
    if (kc < 25) {
      an = Ap[(kc + 1) * 64];
#pragma unroll
      for (int s = 0; s < 6; ++s) bn[s] = Bp[s][(kc + 1) * 64];
    }
#pragma unroll
    for (int s = 0; s < 6; ++s)
      C[s] = __builtin_amdgcn_mfma_i32_32x32x32_i8(a, b[s], C[s], 0, 0, 0);
    a = an;
#pragma unroll
    for (int s = 0; s < 6; ++s) b[s] = bn[s];
  }

  double decay = 1.0 / (1.0 + exp(-(double)tau0[0]));
  int o = nt * 32 + (lane & 31);
  int rbase = 4 * (lane >> 5);
#pragma unroll
  for (int r = 0; r < 16; ++r) {
    int row = (r & 3) + 8 * (r >> 2) + rbase;
    int bi = mt * 32 + row;
    long long T = (long long)C[5][r];
    T = (T << 8) + (long long)C[4][r];
    T = (T << 8) + (long long)C[3][r];
    T = (T << 8) + (long long)C[2][r];
    T = (T << 8) + (long long)C[1][r];
    T = (T << 8) + (long long)C[0][r];
    double I = (double)T * 0x1p-48;
    size_t off = (size_t)bi * 1024 + o;
    double m = h1m[off];
    double so = (double)h1sb[off];
    m = m * decay * (1.0 - so) + I;
    bool sp = (m - 1.0) >= 0.0;
    h1m[off] = m;
    h1sb[off] = sp ? 1 : 0;
  }
}

// ---------------------------------------------------------------------------
// layer2 + pool + accumulator: 32 blocks (m-tiles), 4 waves = n-tiles of 32
// (N=128, o>=100 padded with zero weights -> never spikes). K=1024 chunks of
// 32 read straight from h1sb (row-major == A-frag layout).
// ---------------------------------------------------------------------------
__global__ __launch_bounds__(256) void layer2_kernel(
    const signed char* __restrict__ Bf2, const signed char* __restrict__ h1sb,
    double* __restrict__ h2m, signed char* __restrict__ h2sb,
    double* __restrict__ accum,
    const float* __restrict__ tauv, const float* __restrict__ acct,
    int t, float* __restrict__ out) {
  __shared__ signed char spl[32][128];
  int lane = threadIdx.x & 63;
  int nt = threadIdx.x >> 6;        // 0..3
  int mt = blockIdx.x;              // 0..31
  int m0 = mt * 32 + (lane & 31);

  const i32x4* Ap = (const i32x4*)(h1sb + (size_t)m0 * 1024 + ((lane >> 5) << 4));
  const i32x4* Bp[6];
#pragma unroll
  for (int s = 0; s < 6; ++s)
    Bp[s] = (const i32x4*)Bf2 + (size_t)(s * 4 + nt) * 32 * 64 + lane;

  i32x16 C[6];
#pragma unroll
  for (int s = 0; s < 6; ++s)
#pragma unroll
    for (int i = 0; i < 16; ++i) C[s][i] = 0;

  i32x4 a = Ap[0];
  i32x4 b[6];
#pragma unroll
  for (int s = 0; s < 6; ++s) b[s] = Bp[s][0];

  for (int kc = 0; kc < 32; ++kc) {
    i32x4 an;
    i32x4 bn[6];
    if (kc < 31) {
      an = Ap[(kc + 1) * 2];        // chunk stride 32 bytes = 2 x i32x4
#pragma unroll
      for (int s = 0; s < 6; ++s) bn[s] = Bp[s][(kc + 1) * 64];
    }
#pragma unroll
    for (int s = 0; s < 6; ++s)
      C[s] = __builtin_amdgcn_mfma_i32_32x32x32_i8(a, b[s], C[s], 0, 0, 0);
    a = an;
#pragma unroll
    for (int s = 0; s < 6; ++s) b[s] = bn[s];
  }

  double decayv = 1.0 / (1.0 + exp(-(double)tauv[0]));
  int o = nt * 32 + (lane & 31);
  int rbase = 4 * (lane >> 5);
#pragma unroll
  for (int r = 0; r < 16; ++r) {
    int row = (r & 3) + 8 * (r >> 2) + rbase;
    int bi = mt * 32 + row;
    long long T = (long long)C[5][r];
    T = (T << 8) + (long long)C[4][r];
    T = (T << 8) + (long long)C[3][r];
    T = (T << 8) + (long long)C[2][r];
    T = (T << 8) + (long long)C[1][r];
    T = (T << 8) + (long long)C[0][r];
    double I = (double)T * 0x1p-48;
    size_t off = (size_t)bi * 128 + o;
    double m = h2m[off];
    double so = (double)h2sb[off];
    m = m * decayv * (1.0 - so) + I;
    bool sp = (m - 1.0) >= 0.0;
    h2m[off] = m;
    signed char sb = sp ? 1 : 0;
    h2sb[off] = sb;
    spl[row][o] = sb;
  }
  __syncthreads();

  double accdec = 1.0 / (1.0 + exp(-(double)acct[0]));
#pragma unroll
  for (int it = 0; it < 2; ++it) {
    int task = it * 256 + threadIdx.x;
    if (task < 320) {
      int row = task / 10;
      int g = task % 10;
      int isum = 0;
#pragma unroll
      for (int k = 0; k < 10; ++k) isum += spl[row][g * 10 + k];
      double boost = (double)isum / 10.0;
      int bi = mt * 32 + row;
      double av = accum[bi * 16 + g];
      av = av * accdec + boost;
      accum[bi * 16 + g] = av;
      if (t == NSTEPS - 1) out[bi * 10 + g] = (float)av;
    }
  }
}

// ---------------------------------------------------------------------------
extern "C" void kernel_launch(void* const* d_in, const int* in_sizes, int n_in,
                              void* d_out, int out_size, void* d_ws, size_t ws_size,
                              hipStream_t stream) {
  const float* x    = (const float*)d_in[0];
  const float* W1   = (const float*)d_in[1];
  const float* W2   = (const float*)d_in[2];
  const float* tau0 = (const float*)d_in[3];
  const float* tauv = (const float*)d_in[4];
  const float* acct = (const float*)d_in[5];
  float* out = (float*)d_out;
  char*  ws  = (char*)d_ws;

  signed char* Af  = (signed char*)(ws + OFF_AFRAG);
  signed char* B1  = (signed char*)(ws + OFF_BF1);
  signed char* B2  = (signed char*)(ws + OFF_BF2);
  double* h1m      = (double*)(ws + OFF_H1M);
  signed char* h1sb= (signed char*)(ws + OFF_H1SB);
  double* h2m      = (double*)(ws + OFF_H2M);
  signed char* h2sb= (signed char*)(ws + OFF_H2SB);
  double* accum    = (double*)(ws + OFF_ACC);

  prep_kernel<<<(6 * 32 * 26 * 1024 + 6 * 4 * 32 * 1024 + 255) / 256, 256, 0, stream>>>(
      W1, W2, B1, B2);
  init_kernel<<<(1024 * 1024 + 255) / 256, 256, 0, stream>>>(
      h1m, h2m, (int*)h1sb, (int*)h2sb, accum);
  spikegen_kernel<<<50 * 32 * 26 / 4, 256, 0, stream>>>(x, (i32x4*)Af);

  for (int t = 0; t < NSTEPS; ++t) {
    layer1_kernel<<<dim3(8, 32), 256, 0, stream>>>(B1, Af, h1m, h1sb, tau0, t);
    layer2_kernel<<<32, 256, 0, stream>>>(B2, h1sb, h2m, h2sb, accum,
                                          tauv, acct, t, out);
  }
}

// Round 3
// 614.434 us; speedup vs baseline: 16.0413x; 3.3698x over previous
//
#include <hip/hip_runtime.h>
#include <hip/hip_bf16.h>
#include <math.h>

// ---------------------------------------------------------------------------
// sMLP4, time-parallel formulation (exact int8-sliced MFMA):
//   spikegen(t-chunk) -> GEMM1 [M=C*1024,N=1024,K=832]x6 slices -> rec1
//   (elementwise fp64 recurrence, membranes in regs) -> GEMM2
//   [M=C*1024,N=128,K=1024]x6 -> rec2 + pool + accumulator.
//   All sums exact: T = Horner(int32 slice dots), I = (double)T*2^-48.
//   Trajectory bit-identical to the passing round-1/2 kernels.
// ---------------------------------------------------------------------------

#define NSTEPS 50

typedef __attribute__((ext_vector_type(4)))  int i32x4;
typedef __attribute__((ext_vector_type(16))) int i32x16;

// fixed workspace layout (bytes, all 256-aligned)
#define OFF_B1     0ull            // i8 [6*32*26*1024] = 5,111,808
#define OFF_B2     5111808ull      // i8 [6*4*32*1024]  =   786,432
#define OFF_H1MST  5898240ull      // f64[1024*1024]    = 8,388,608
#define OFF_H1SST  14286848ull     // i8 [1024*1024]    = 1,048,576
#define OFF_H2MST  15335424ull     // f64[1024*128]     = 1,048,576
#define OFF_H2SST  16384000ull     // i8 [1024*128]     =   131,072
#define OFF_ACCST  16515072ull     // f64[1024*10]      =    81,920
#define FIXED_END  16596992ull
// per-chunk (C steps): Afc C*851,968 ; T1 C*8,388,608 ; h1sc C*1,048,576 ;
//                      T2 C*1,048,576  -> 11,337,728 per step
#define PERSTEP    11337728ull

// ---------------------------------------------------------------------------
// threefry2x32, key (0,42), partitionable mode: bits(i) = x0^x1 on ctr (0,i)
// ---------------------------------------------------------------------------
__device__ __forceinline__ unsigned int rotl32(unsigned int v, int d) {
  return (v << d) | (v >> (32 - d));
}

__device__ __forceinline__ unsigned int tf_bits(unsigned int i) {
  const unsigned int ks0 = 0u;
  const unsigned int ks1 = 42u;
  const unsigned int ks2 = 0x1BD11BDAu ^ 0u ^ 42u;
  unsigned int x0 = 0u + ks0;
  unsigned int x1 = i + ks1;
#define TF_RND(r) { x0 += x1; x1 = rotl32(x1, r); x1 ^= x0; }
  TF_RND(13) TF_RND(15) TF_RND(26) TF_RND(6)
  x0 += ks1; x1 += ks2 + 1u;
  TF_RND(17) TF_RND(29) TF_RND(16) TF_RND(24)
  x0 += ks2; x1 += ks0 + 2u;
  TF_RND(13) TF_RND(15) TF_RND(26) TF_RND(6)
  x0 += ks0; x1 += ks1 + 3u;
  TF_RND(17) TF_RND(29) TF_RND(16) TF_RND(24)
  x0 += ks1; x1 += ks2 + 4u;
  TF_RND(13) TF_RND(15) TF_RND(26) TF_RND(6)
  x0 += ks2; x1 += ks0 + 5u;
#undef TF_RND
  return x0 ^ x1;
}

// ---------------------------------------------------------------------------
// prep: fp32 weights -> 6 signed base-256 digit slices in MFMA B-frag order.
// B-frag (32x32x32 i8): lane holds B[k = kc*32+(lane>>5)*16+jj][n],
// n = nt*32+(lane&31). (identical to round-2 layout, HW-validated)
// ---------------------------------------------------------------------------
__global__ __launch_bounds__(256) void prep_kernel(
    const float* __restrict__ W1, const float* __restrict__ W2,
    signed char* __restrict__ B1, signed char* __restrict__ B2) {
  int idx = blockIdx.x * 256 + threadIdx.x;
  const int NB1 = 6 * 32 * 26 * 1024;
  const int NB2 = 6 * 4 * 32 * 1024;
  float w;
  int s;
  signed char* dst;
  if (idx < NB1) {
    int jj = idx & 15;
    int lane = (idx >> 4) & 63;
    int kc = (idx >> 10) % 26;
    int rest = (idx >> 10) / 26;
    int nt = rest & 31;
    s = rest >> 5;
    int k = kc * 32 + ((lane >> 5) << 4) + jj;
    int o = nt * 32 + (lane & 31);
    w = (o < 1000 && k < 784) ? W1[o * 784 + k] : 0.0f;
    dst = B1 + idx;
  } else if (idx < NB1 + NB2) {
    int m = idx - NB1;
    int jj = m & 15;
    int lane = (m >> 4) & 63;
    int kc = (m >> 10) & 31;
    int rest = (m >> 10) >> 5;
    int nt = rest & 3;
    s = rest >> 2;
    int k = kc * 32 + ((lane >> 5) << 4) + jj;
    int o = nt * 32 + (lane & 31);
    w = (o < 100 && k < 1000) ? W2[o * 1000 + k] : 0.0f;
    dst = B2 + m;
  } else {
    return;
  }
  long long V = llrint((double)w * 281474976710656.0);  // w * 2^48, exact
  signed char d = 0;
  for (int q = 0; q <= s; ++q) {
    d = (signed char)(V & 0xFF);
    V = (V - (long long)d) >> 8;
  }
  *dst = d;
}

// ---------------------------------------------------------------------------
// spikegen (chunk of C steps): spike bytes in GEMM1 A-frag order.
// A-frag: lane holds A[m = mt*32+(lane&31)][k = kc*32+(lane>>5)*16+jj].
// ---------------------------------------------------------------------------
__global__ __launch_bounds__(256) void spikegen_kernel(
    const float* __restrict__ x, i32x4* __restrict__ A, int t0) {
  int g = blockIdx.x * 4 + (threadIdx.x >> 6);   // (tl*32+mt)*26+kc
  int lane = threadIdx.x & 63;
  int kc = g % 26;
  int r = g / 26;
  int mt = r & 31;
  int tl = r >> 5;
  int t = t0 + tl;
  int b = mt * 32 + (lane & 31);
  int j0 = kc * 32 + ((lane >> 5) << 4);
  unsigned int wds[4] = {0u, 0u, 0u, 0u};
#pragma unroll
  for (int jj = 0; jj < 16; ++jj) {
    int j = j0 + jj;
    if (j < 784) {
      unsigned int i = (unsigned int)(t * 1024 + b) * 784u + (unsigned int)j;
      unsigned int bits = tf_bits(i);
      float u = __uint_as_float((bits >> 9) | 0x3f800000u) - 1.0f;
      if (u < x[b * 784 + j]) wds[jj >> 2] |= 1u << (8 * (jj & 3));
    }
  }
  i32x4 v;
  v.x = (int)wds[0]; v.y = (int)wds[1]; v.z = (int)wds[2]; v.w = (int)wds[3];
  A[(size_t)g * 64 + lane] = v;
}

// ---------------------------------------------------------------------------
// GEMM1: M=C*1024 (t-batched), N=1024, K=832, 6 slices.
// Block = 4 waves sharing one nt (B staged in LDS, double-buffered), each
// wave one 32x32 m-tile. 2-deep register prefetch on A and B-stage.
// ---------------------------------------------------------------------------
__global__ __launch_bounds__(256, 2) void gemm1_kernel(
    const signed char* __restrict__ Bf, const signed char* __restrict__ Afc,
    double* __restrict__ T1) {
  __shared__ i32x4 bls[2][6][64];
  int tid = threadIdx.x, lane = tid & 63, wv = tid >> 6;
  int nt = blockIdx.x;                 // 0..31
  int mg = blockIdx.y;
  int tl = mg >> 3;
  int mt = ((mg & 7) << 2) + wv;       // 0..31
  const i32x4* Ap = (const i32x4*)Afc + (size_t)((tl * 32 + mt) * 26) * 64 + lane;
  const i32x4* Bp = (const i32x4*)Bf + lane;
  const int s0 = wv, s1 = wv + 4;
  const bool has2 = (wv < 2);
#define B1_IDX(s, kc) ((size_t)(((s) * 32 + nt) * 26 + (kc)) * 64)

  i32x16 C[6];
#pragma unroll
  for (int s = 0; s < 6; ++s)
#pragma unroll
    for (int i = 0; i < 16; ++i) C[s][i] = 0;

  i32x4 sa = Bp[B1_IDX(s0, 0)];
  i32x4 sb; if (has2) sb = Bp[B1_IDX(s1, 0)];
  i32x4 a0 = Ap[0], a1 = Ap[64], a2;
  bls[0][s0][lane] = sa;
  if (has2) bls[0][s1][lane] = sb;
  sa = Bp[B1_IDX(s0, 1)];
  if (has2) sb = Bp[B1_IDX(s1, 1)];
  __syncthreads();

  for (int kc = 0; kc < 26; ++kc) {
    const int cur = kc & 1, nxt = cur ^ 1;
    if (kc + 1 < 26) {
      bls[nxt][s0][lane] = sa;
      if (has2) bls[nxt][s1][lane] = sb;
    }
    if (kc + 2 < 26) {
      sa = Bp[B1_IDX(s0, kc + 2)];
      if (has2) sb = Bp[B1_IDX(s1, kc + 2)];
      a2 = Ap[(size_t)(kc + 2) * 64];
    }
    i32x4 b0 = bls[cur][0][lane], b1 = bls[cur][1][lane], b2 = bls[cur][2][lane];
    i32x4 b3 = bls[cur][3][lane], b4 = bls[cur][4][lane], b5 = bls[cur][5][lane];
    C[0] = __builtin_amdgcn_mfma_i32_32x32x32_i8(a0, b0, C[0], 0, 0, 0);
    C[1] = __builtin_amdgcn_mfma_i32_32x32x32_i8(a0, b1, C[1], 0, 0, 0);
    C[2] = __builtin_amdgcn_mfma_i32_32x32x32_i8(a0, b2, C[2], 0, 0, 0);
    C[3] = __builtin_amdgcn_mfma_i32_32x32x32_i8(a0, b3, C[3], 0, 0, 0);
    C[4] = __builtin_amdgcn_mfma_i32_32x32x32_i8(a0, b4, C[4], 0, 0, 0);
    C[5] = __builtin_amdgcn_mfma_i32_32x32x32_i8(a0, b5, C[5], 0, 0, 0);
    a0 = a1; a1 = a2;
    __syncthreads();
  }

  int o = nt * 32 + (lane & 31);
  int rb = 4 * (lane >> 5);
#pragma unroll
  for (int r = 0; r < 16; ++r) {
    int row = (r & 3) + 8 * (r >> 2) + rb;
    int b = mt * 32 + row;
    long long T = (long long)C[5][r];
    T = (T << 8) + (long long)C[4][r];
    T = (T << 8) + (long long)C[3][r];
    T = (T << 8) + (long long)C[2][r];
    T = (T << 8) + (long long)C[1][r];
    T = (T << 8) + (long long)C[0][r];
    T1[((size_t)tl * 1024 + b) * 1024 + o] = (double)T * 0x1p-48;
  }
}

// ---------------------------------------------------------------------------
// rec1: layer-1 membrane recurrence, elementwise over (b,o), sequential in t.
// Thread owns 8 elements (o = half*512 + 64j + lane), membranes in registers.
// ---------------------------------------------------------------------------
__global__ __launch_bounds__(256) void rec1_kernel(
    const double* __restrict__ T1, signed char* __restrict__ h1sc,
    double* __restrict__ h1m_st, signed char* __restrict__ h1s_st,
    const float* __restrict__ tau0, int t0, int C) {
  int tid = threadIdx.x;
  int lane = tid & 63, sub = tid >> 6;
  int b = blockIdx.x * 2 + (sub >> 1);
  int obase = (sub & 1) * 512 + lane;           // o = obase + 64*j
  double alpha = 1.0 / (1.0 + exp(-(double)tau0[0]));
  double m[8], s[8];
  if (t0 == 0) {
#pragma unroll
    for (int j = 0; j < 8; ++j) { m[j] = 0.5; s[j] = 0.0; }
  } else {
#pragma unroll
    for (int j = 0; j < 8; ++j) {
      m[j] = h1m_st[(size_t)b * 1024 + obase + 64 * j];
      s[j] = (double)h1s_st[(size_t)b * 1024 + obase + 64 * j];
    }
  }
  for (int tl = 0; tl < C; ++tl) {
    const double* Ip = T1 + ((size_t)tl * 1024 + b) * 1024 + obase;
    signed char* Sp = h1sc + ((size_t)tl * 1024 + b) * 1024 + obase;
#pragma unroll
    for (int j = 0; j < 8; ++j) {
      double I = Ip[64 * j];
      m[j] = (s[j] != 0.0 ? 0.0 : m[j] * alpha) + I;
      bool sp = (m[j] - 1.0) >= 0.0;
      s[j] = sp ? 1.0 : 0.0;
      Sp[64 * j] = sp ? 1 : 0;
    }
  }
#pragma unroll
  for (int j = 0; j < 8; ++j) {
    h1m_st[(size_t)b * 1024 + obase + 64 * j] = m[j];
    h1s_st[(size_t)b * 1024 + obase + 64 * j] = (signed char)(s[j] != 0.0 ? 1 : 0);
  }
}

// ---------------------------------------------------------------------------
// GEMM2: M=C*1024, N=128, K=1024, 6 slices. A = h1sc bytes row-major
// (row stride 1024 == A-frag k-order). Same LDS-staged structure.
// ---------------------------------------------------------------------------
__global__ __launch_bounds__(256, 2) void gemm2_kernel(
    const signed char* __restrict__ Bf, const signed char* __restrict__ h1sc,
    double* __restrict__ T2) {
  __shared__ i32x4 bls[2][6][64];
  int tid = threadIdx.x, lane = tid & 63, wv = tid >> 6;
  int nt = blockIdx.x;                 // 0..3
  int mg = blockIdx.y;
  int tl = mg >> 3;
  int mt = ((mg & 7) << 2) + wv;
  const signed char* Arow =
      h1sc + ((size_t)tl * 1024 + mt * 32 + (lane & 31)) * 1024 + ((lane >> 5) << 4);
  const i32x4* Bp = (const i32x4*)Bf + lane;
  const int s0 = wv, s1 = wv + 4;
  const bool has2 = (wv < 2);
#define B2_IDX(s, kc) ((size_t)(((s) * 4 + nt) * 32 + (kc)) * 64)

  i32x16 C[6];
#pragma unroll
  for (int s = 0; s < 6; ++s)
#pragma unroll
    for (int i = 0; i < 16; ++i) C[s][i] = 0;

  i32x4 sa = Bp[B2_IDX(s0, 0)];
  i32x4 sb; if (has2) sb = Bp[B2_IDX(s1, 0)];
  i32x4 a0 = *(const i32x4*)(Arow);
  i32x4 a1 = *(const i32x4*)(Arow + 32);
  i32x4 a2;
  bls[0][s0][lane] = sa;
  if (has2) bls[0][s1][lane] = sb;
  sa = Bp[B2_IDX(s0, 1)];
  if (has2) sb = Bp[B2_IDX(s1, 1)];
  __syncthreads();

  for (int kc = 0; kc < 32; ++kc) {
    const int cur = kc & 1, nxt = cur ^ 1;
    if (kc + 1 < 32) {
      bls[nxt][s0][lane] = sa;
      if (has2) bls[nxt][s1][lane] = sb;
    }
    if (kc + 2 < 32) {
      sa = Bp[B2_IDX(s0, kc + 2)];
      if (has2) sb = Bp[B2_IDX(s1, kc + 2)];
      a2 = *(const i32x4*)(Arow + (size_t)(kc + 2) * 32);
    }
    i32x4 b0 = bls[cur][0][lane], b1 = bls[cur][1][lane], b2 = bls[cur][2][lane];
    i32x4 b3 = bls[cur][3][lane], b4 = bls[cur][4][lane], b5 = bls[cur][5][lane];
    C[0] = __builtin_amdgcn_mfma_i32_32x32x32_i8(a0, b0, C[0], 0, 0, 0);
    C[1] = __builtin_amdgcn_mfma_i32_32x32x32_i8(a0, b1, C[1], 0, 0, 0);
    C[2] = __builtin_amdgcn_mfma_i32_32x32x32_i8(a0, b2, C[2], 0, 0, 0);
    C[3] = __builtin_amdgcn_mfma_i32_32x32x32_i8(a0, b3, C[3], 0, 0, 0);
    C[4] = __builtin_amdgcn_mfma_i32_32x32x32_i8(a0, b4, C[4], 0, 0, 0);
    C[5] = __builtin_amdgcn_mfma_i32_32x32x32_i8(a0, b5, C[5], 0, 0, 0);
    a0 = a1; a1 = a2;
    __syncthreads();
  }

  int o = nt * 32 + (lane & 31);
  int rb = 4 * (lane >> 5);
#pragma unroll
  for (int r = 0; r < 16; ++r) {
    int row = (r & 3) + 8 * (r >> 2) + rb;
    int b = mt * 32 + row;
    long long T = (long long)C[5][r];
    T = (T << 8) + (long long)C[4][r];
    T = (T << 8) + (long long)C[3][r];
    T = (T << 8) + (long long)C[2][r];
    T = (T << 8) + (long long)C[1][r];
    T = (T << 8) + (long long)C[0][r];
    T2[((size_t)tl * 1024 + b) * 128 + o] = (double)T * 0x1p-48;
  }
}

// ---------------------------------------------------------------------------
// rec2: layer-2 membrane recurrence + AvgPool(10) + pPLI accumulator.
// Block = 2 batch rows x 128 outputs; membranes/acc in registers.
// ---------------------------------------------------------------------------
__global__ __launch_bounds__(256) void rec2_kernel(
    const double* __restrict__ T2, double* __restrict__ h2m_st,
    signed char* __restrict__ h2s_st, double* __restrict__ acc_st,
    const float* __restrict__ tauv, const float* __restrict__ acct,
    int t0, int C, float* __restrict__ out) {
  __shared__ signed char sp[256];
  int tid = threadIdx.x;
  int b = blockIdx.x * 2 + (tid >> 7);
  int o = tid & 127;
  double alpha = 1.0 / (1.0 + exp(-(double)tauv[0]));
  double adec  = 1.0 / (1.0 + exp(-(double)acct[0]));
  double m, s, accv = 0.0;
  bool isPool = (o < 10);
  if (t0 == 0) {
    m = 0.5; s = 0.0;
  } else {
    m = h2m_st[(size_t)b * 128 + o];
    s = (double)h2s_st[(size_t)b * 128 + o];
    if (isPool) accv = acc_st[b * 10 + o];
  }
  for (int tl = 0; tl < C; ++tl) {
    double I = T2[((size_t)tl * 1024 + b) * 128 + o];
    m = (s != 0.0 ? 0.0 : m * alpha) + I;
    bool spk = (m - 1.0) >= 0.0;
    s = spk ? 1.0 : 0.0;
    sp[tid] = spk ? 1 : 0;
    __syncthreads();
    if (isPool) {
      int base = tid & 128;
      int isum = 0;
#pragma unroll
      for (int k = 0; k < 10; ++k) isum += sp[base + o * 10 + k];
      accv = accv * adec + (double)isum / 10.0;
      if (t0 + tl == NSTEPS - 1) out[b * 10 + o] = (float)accv;
    }
    __syncthreads();
  }
  h2m_st[(size_t)b * 128 + o] = m;
  h2s_st[(size_t)b * 128 + o] = (signed char)(s != 0.0 ? 1 : 0);
  if (isPool) acc_st[b * 10 + o] = accv;
}

// ---------------------------------------------------------------------------
extern "C" void kernel_launch(void* const* d_in, const int* in_sizes, int n_in,
                              void* d_out, int out_size, void* d_ws, size_t ws_size,
                              hipStream_t stream) {
  const float* x    = (const float*)d_in[0];
  const float* W1   = (const float*)d_in[1];
  const float* W2   = (const float*)d_in[2];
  const float* tau0 = (const float*)d_in[3];
  const float* tauv = (const float*)d_in[4];
  const float* acct = (const float*)d_in[5];
  float* out = (float*)d_out;
  char*  ws  = (char*)d_ws;

  signed char* B1     = (signed char*)(ws + OFF_B1);
  signed char* B2     = (signed char*)(ws + OFF_B2);
  double*      h1m_st = (double*)(ws + OFF_H1MST);
  signed char* h1s_st = (signed char*)(ws + OFF_H1SST);
  double*      h2m_st = (double*)(ws + OFF_H2MST);
  signed char* h2s_st = (signed char*)(ws + OFF_H2SST);
  double*      acc_st = (double*)(ws + OFF_ACCST);

  // adaptive chunking: per-chunk buffers sized C steps
  long long avail = (long long)ws_size - (long long)FIXED_END;
  int C = (int)(avail / (long long)PERSTEP);
  if (C < 1) C = 1;
  if (C > NSTEPS) C = NSTEPS;
  size_t off_afc  = FIXED_END;
  size_t off_t1   = off_afc + (size_t)C * 851968ull;
  size_t off_h1sc = off_t1  + (size_t)C * 8388608ull;
  size_t off_t2   = off_h1sc + (size_t)C * 1048576ull;
  signed char* Afc  = (signed char*)(ws + off_afc);
  double*      T1   = (double*)(ws + off_t1);
  signed char* h1sc = (signed char*)(ws + off_h1sc);
  double*      T2   = (double*)(ws + off_t2);

  prep_kernel<<<(6 * 32 * 26 * 1024 + 6 * 4 * 32 * 1024 + 255) / 256, 256, 0, stream>>>(
      W1, W2, B1, B2);

  for (int t0 = 0; t0 < NSTEPS; t0 += C) {
    int Cc = (NSTEPS - t0 < C) ? (NSTEPS - t0) : C;
    spikegen_kernel<<<Cc * 208, 256, 0, stream>>>(x, (i32x4*)Afc, t0);
    gemm1_kernel<<<dim3(32, Cc * 8), 256, 0, stream>>>(B1, Afc, T1);
    rec1_kernel<<<512, 256, 0, stream>>>(T1, h1sc, h1m_st, h1s_st, tau0, t0, Cc);
    gemm2_kernel<<<dim3(4, Cc * 8), 256, 0, stream>>>(B2, h1sc, T2);
    rec2_kernel<<<512, 256, 0, stream>>>(T2, h2m_st, h2s_st, acc_st,
                                         tauv, acct, t0, Cc, out);
  }
}

// Round 4
// 584.341 us; speedup vs baseline: 16.8674x; 1.0515x over previous
//
#include <hip/hip_runtime.h>
#include <hip/hip_bf16.h>
#include <math.h>

// ---------------------------------------------------------------------------
// sMLP4, time-parallel formulation (exact int8-sliced MFMA):
//   spikegen(all 50 steps) -> per chunk: GEMM1 [M=C*1024,N=1024,K=800]x6 ->
//   rec1 (elementwise fp64 recurrence) -> GEMM2 [M=C*1024,N=128,K=1024]x6 ->
//   rec2 + pool + accumulator.
//   All sums exact: T = Horner(int32 slice dots), I = (double)T*2^-48.
//   Trajectory bit-identical to the passing round-1/2/3 kernels.
// Round 4: gemm1 2 m-tiles/wave (12 MFMA per 6 ds_read -> MFMA-bound),
//   KC=25 (drop all-zero k-chunk), spikegen alignbit+int-compare+1 launch,
//   C capped at 13 for LLC residency.
// ---------------------------------------------------------------------------

#define NSTEPS 50
#define KC1 25                     // real K chunks for layer 1 (800 >= 784)

typedef __attribute__((ext_vector_type(4)))  int i32x4;
typedef __attribute__((ext_vector_type(16))) int i32x16;

// fixed workspace layout (bytes, all 256-aligned)
#define OFF_B1     0ull            // i8 [6*32*26*1024] = 5,111,808
#define OFF_B2     5111808ull      // i8 [6*4*32*1024]  =   786,432
#define OFF_H1MST  5898240ull      // f64[1024*1024]    = 8,388,608
#define OFF_H1SST  14286848ull     // i8 [1024*1024]    = 1,048,576
#define OFF_H2MST  15335424ull     // f64[1024*128]     = 1,048,576
#define OFF_H2SST  16384000ull     // i8 [1024*128]     =   131,072
#define OFF_ACCST  16515072ull     // f64[1024*10]      =    81,920
#define OFF_AF     16596992ull     // i8 [50*32*26*64*16] = 42,598,400
#define FIXED_END  59195392ull
// per-chunk (C steps): T1 C*8,388,608 ; h1sc C*1,048,576 ; T2 C*1,048,576
#define PERSTEP    10485760ull

// ---------------------------------------------------------------------------
// threefry2x32, key (0,42), partitionable mode: bits(i) = x0^x1 on ctr (0,i)
// ---------------------------------------------------------------------------
__device__ __forceinline__ unsigned int rotl32(unsigned int v, int d) {
#if __has_builtin(__builtin_amdgcn_alignbit)
  return __builtin_amdgcn_alignbit(v, v, (unsigned int)(32 - d));
#else
  return (v << d) | (v >> (32 - d));
#endif
}

__device__ __forceinline__ unsigned int tf_bits(unsigned int i) {
  const unsigned int ks0 = 0u;
  const unsigned int ks1 = 42u;
  const unsigned int ks2 = 0x1BD11BDAu ^ 0u ^ 42u;
  unsigned int x0 = 0u + ks0;
  unsigned int x1 = i + ks1;
#define TF_RND(r) { x0 += x1; x1 = rotl32(x1, r); x1 ^= x0; }
  TF_RND(13) TF_RND(15) TF_RND(26) TF_RND(6)
  x0 += ks1; x1 += ks2 + 1u;
  TF_RND(17) TF_RND(29) TF_RND(16) TF_RND(24)
  x0 += ks2; x1 += ks0 + 2u;
  TF_RND(13) TF_RND(15) TF_RND(26) TF_RND(6)
  x0 += ks0; x1 += ks1 + 3u;
  TF_RND(17) TF_RND(29) TF_RND(16) TF_RND(24)
  x0 += ks1; x1 += ks2 + 4u;
  TF_RND(13) TF_RND(15) TF_RND(26) TF_RND(6)
  x0 += ks2; x1 += ks0 + 5u;
#undef TF_RND
  return x0 ^ x1;
}

// ---------------------------------------------------------------------------
// prep: fp32 weights -> 6 signed base-256 digit slices in MFMA B-frag order.
// B-frag (32x32x32 i8): lane holds B[k = kc*32+(lane>>5)*16+jj][n],
// n = nt*32+(lane&31). (HW-validated layout)
// ---------------------------------------------------------------------------
__global__ __launch_bounds__(256) void prep_kernel(
    const float* __restrict__ W1, const float* __restrict__ W2,
    signed char* __restrict__ B1, signed char* __restrict__ B2) {
  int idx = blockIdx.x * 256 + threadIdx.x;
  const int NB1 = 6 * 32 * 26 * 1024;
  const int NB2 = 6 * 4 * 32 * 1024;
  float w;
  int s;
  signed char* dst;
  if (idx < NB1) {
    int jj = idx & 15;
    int lane = (idx >> 4) & 63;
    int kc = (idx >> 10) % 26;
    int rest = (idx >> 10) / 26;
    int nt = rest & 31;
    s = rest >> 5;
    int k = kc * 32 + ((lane >> 5) << 4) + jj;
    int o = nt * 32 + (lane & 31);
    w = (o < 1000 && k < 784) ? W1[o * 784 + k] : 0.0f;
    dst = B1 + idx;
  } else if (idx < NB1 + NB2) {
    int m = idx - NB1;
    int jj = m & 15;
    int lane = (m >> 4) & 63;
    int kc = (m >> 10) & 31;
    int rest = (m >> 10) >> 5;
    int nt = rest & 3;
    s = rest >> 2;
    int k = kc * 32 + ((lane >> 5) << 4) + jj;
    int o = nt * 32 + (lane & 31);
    w = (o < 100 && k < 1000) ? W2[o * 1000 + k] : 0.0f;
    dst = B2 + m;
  } else {
    return;
  }
  long long V = llrint((double)w * 281474976710656.0);  // w * 2^48, exact
  signed char d = 0;
  for (int q = 0; q <= s; ++q) {
    d = (signed char)(V & 0xFF);
    V = (V - (long long)d) >> 8;
  }
  *dst = d;
}

// ---------------------------------------------------------------------------
// spikegen (all 50 steps): spike bytes in GEMM1 A-frag order.
// A-frag: lane holds A[m = mt*32+(lane&31)][k = kc*32+(lane>>5)*16+jj].
// Only kc<25 generated (j>=784 region never read by gemm1).
// Integer compare: u < x  <=>  (bits>>9) < ceil(x*2^23)   (both exact).
// ---------------------------------------------------------------------------
__global__ __launch_bounds__(256) void spikegen_kernel(
    const float* __restrict__ x, i32x4* __restrict__ A) {
  int g = blockIdx.x * 4 + (threadIdx.x >> 6);   // (t*32+mt)*25+kc
  int lane = threadIdx.x & 63;
  int kc = g % 25;
  int r = g / 25;
  int mt = r & 31;
  int t = r >> 5;
  int b = mt * 32 + (lane & 31);
  int j0 = kc * 32 + ((lane >> 5) << 4);
  unsigned int wds[4] = {0u, 0u, 0u, 0u};
  if (j0 < 784) {                                // 784 = 49*16: block-uniform
    unsigned int base = (unsigned int)(t * 1024 + b) * 784u + (unsigned int)j0;
    const float* xp = x + b * 784 + j0;
#pragma unroll
    for (int q = 0; q < 4; ++q) {
      float4 xv = *(const float4*)(xp + 4 * q);
      unsigned int K0 = (unsigned int)(int)ceilf(xv.x * 8388608.0f);
      unsigned int K1 = (unsigned int)(int)ceilf(xv.y * 8388608.0f);
      unsigned int K2 = (unsigned int)(int)ceilf(xv.z * 8388608.0f);
      unsigned int K3 = (unsigned int)(int)ceilf(xv.w * 8388608.0f);
      unsigned int w4 = 0u;
      if ((tf_bits(base + 4 * q + 0) >> 9) < K0) w4 |= 1u;
      if ((tf_bits(base + 4 * q + 1) >> 9) < K1) w4 |= 1u << 8;
      if ((tf_bits(base + 4 * q + 2) >> 9) < K2) w4 |= 1u << 16;
      if ((tf_bits(base + 4 * q + 3) >> 9) < K3) w4 |= 1u << 24;
      wds[q] = w4;
    }
  }
  i32x4 v;
  v.x = (int)wds[0]; v.y = (int)wds[1]; v.z = (int)wds[2]; v.w = (int)wds[3];
  A[(size_t)((r * 26) + kc) * 64 + lane] = v;    // layout keeps stride 26
}

// ---------------------------------------------------------------------------
// GEMM1: M=C*1024 (t-batched), N=1024, K=800 (25 chunks), 6 slices.
// Block = 4 waves sharing one nt (B staged in LDS, double-buffered); each
// wave computes TWO 32x32 m-tiles (12 MFMA per 6 ds_read -> MFMA-bound).
// ~250 combined VGPR -> 1 wave/SIMD.
// ---------------------------------------------------------------------------
__global__ __launch_bounds__(256, 1) void gemm1_kernel(
    const signed char* __restrict__ Bf, const signed char* __restrict__ Afc,
    double* __restrict__ T1) {
  __shared__ i32x4 bls[2][6][64];
  int tid = threadIdx.x, lane = tid & 63, wv = tid >> 6;
  int nt = blockIdx.x;                 // 0..31
  int mg = blockIdx.y;
  int tl = mg >> 2;
  int q  = mg & 3;
  int mtA = q * 8 + wv * 2;            // and mtA+1
  const i32x4* ApA = (const i32x4*)Afc + (size_t)((tl * 32 + mtA) * 26) * 64 + lane;
  const i32x4* ApB = ApA + 26 * 64;    // m-tile mtA+1
  const i32x4* Bp = (const i32x4*)Bf + lane;
  const int s0 = wv, s1 = wv + 4;
  const bool has2 = (wv < 2);
#define B1_IDX(s, kc) ((size_t)(((s) * 32 + nt) * 26 + (kc)) * 64)

  i32x16 CA[6], CB[6];
#pragma unroll
  for (int s = 0; s < 6; ++s)
#pragma unroll
    for (int i = 0; i < 16; ++i) { CA[s][i] = 0; CB[s][i] = 0; }

  i32x4 sa = Bp[B1_IDX(s0, 0)];
  i32x4 sb; if (has2) sb = Bp[B1_IDX(s1, 0)];
  i32x4 aA0 = ApA[0], aB0 = ApB[0];
  i32x4 aA1 = ApA[64], aB1 = ApB[64];
  i32x4 aA2, aB2;
  bls[0][s0][lane] = sa;
  if (has2) bls[0][s1][lane] = sb;
  sa = Bp[B1_IDX(s0, 1)];
  if (has2) sb = Bp[B1_IDX(s1, 1)];
  __syncthreads();

  for (int kc = 0; kc < KC1; ++kc) {
    const int cur = kc & 1, nxt = cur ^ 1;
    if (kc + 1 < KC1) {
      bls[nxt][s0][lane] = sa;
      if (has2) bls[nxt][s1][lane] = sb;
    }
    if (kc + 2 < KC1) {
      sa = Bp[B1_IDX(s0, kc + 2)];
      if (has2) sb = Bp[B1_IDX(s1, kc + 2)];
      aA2 = ApA[(size_t)(kc + 2) * 64];
      aB2 = ApB[(size_t)(kc + 2) * 64];
    }
#pragma unroll
    for (int s = 0; s < 6; ++s) {
      i32x4 b = bls[cur][s][lane];
      CA[s] = __builtin_amdgcn_mfma_i32_32x32x32_i8(aA0, b, CA[s], 0, 0, 0);
      CB[s] = __builtin_amdgcn_mfma_i32_32x32x32_i8(aB0, b, CB[s], 0, 0, 0);
    }
    aA0 = aA1; aA1 = aA2;
    aB0 = aB1; aB1 = aB2;
    __syncthreads();
  }

  int o = nt * 32 + (lane & 31);
  int rb = 4 * (lane >> 5);
#pragma unroll
  for (int r = 0; r < 16; ++r) {
    int row = (r & 3) + 8 * (r >> 2) + rb;
    long long TA = (long long)CA[5][r];
    TA = (TA << 8) + (long long)CA[4][r];
    TA = (TA << 8) + (long long)CA[3][r];
    TA = (TA << 8) + (long long)CA[2][r];
    TA = (TA << 8) + (long long)CA[1][r];
    TA = (TA << 8) + (long long)CA[0][r];
    long long TB = (long long)CB[5][r];
    TB = (TB << 8) + (long long)CB[4][r];
    TB = (TB << 8) + (long long)CB[3][r];
    TB = (TB << 8) + (long long)CB[2][r];
    TB = (TB << 8) + (long long)CB[1][r];
    TB = (TB << 8) + (long long)CB[0][r];
    int bA = mtA * 32 + row;
    T1[((size_t)tl * 1024 + bA) * 1024 + o]      = (double)TA * 0x1p-48;
    T1[((size_t)tl * 1024 + bA + 32) * 1024 + o] = (double)TB * 0x1p-48;
  }
}

// ---------------------------------------------------------------------------
// rec1: layer-1 membrane recurrence, elementwise over (b,o), sequential in t.
// Thread owns 8 elements (o = half*512 + 64j + lane), membranes in registers.
// ---------------------------------------------------------------------------
__global__ __launch_bounds__(256) void rec1_kernel(
    const double* __restrict__ T1, signed char* __restrict__ h1sc,
    double* __restrict__ h1m_st, signed char* __restrict__ h1s_st,
    const float* __restrict__ tau0, int t0, int C) {
  int tid = threadIdx.x;
  int lane = tid & 63, sub = tid >> 6;
  int b = blockIdx.x * 2 + (sub >> 1);
  int obase = (sub & 1) * 512 + lane;           // o = obase + 64*j
  double alpha = 1.0 / (1.0 + exp(-(double)tau0[0]));
  double m[8], s[8];
  if (t0 == 0) {
#pragma unroll
    for (int j = 0; j < 8; ++j) { m[j] = 0.5; s[j] = 0.0; }
  } else {
#pragma unroll
    for (int j = 0; j < 8; ++j) {
      m[j] = h1m_st[(size_t)b * 1024 + obase + 64 * j];
      s[j] = (double)h1s_st[(size_t)b * 1024 + obase + 64 * j];
    }
  }
  for (int tl = 0; tl < C; ++tl) {
    const double* Ip = T1 + ((size_t)tl * 1024 + b) * 1024 + obase;
    signed char* Sp = h1sc + ((size_t)tl * 1024 + b) * 1024 + obase;
#pragma unroll
    for (int j = 0; j < 8; ++j) {
      double I = Ip[64 * j];
      m[j] = (s[j] != 0.0 ? 0.0 : m[j] * alpha) + I;
      bool sp = (m[j] - 1.0) >= 0.0;
      s[j] = sp ? 1.0 : 0.0;
      Sp[64 * j] = sp ? 1 : 0;
    }
  }
#pragma unroll
  for (int j = 0; j < 8; ++j) {
    h1m_st[(size_t)b * 1024 + obase + 64 * j] = m[j];
    h1s_st[(size_t)b * 1024 + obase + 64 * j] = (signed char)(s[j] != 0.0 ? 1 : 0);
  }
}

// ---------------------------------------------------------------------------
// GEMM2: M=C*1024, N=128, K=1024, 6 slices. A = h1sc bytes row-major
// (row stride 1024 == A-frag k-order). LDS-staged B, double-buffered.
// ---------------------------------------------------------------------------
__global__ __launch_bounds__(256, 2) void gemm2_kernel(
    const signed char* __restrict__ Bf, const signed char* __restrict__ h1sc,
    double* __restrict__ T2) {
  __shared__ i32x4 bls[2][6][64];
  int tid = threadIdx.x, lane = tid & 63, wv = tid >> 6;
  int nt = blockIdx.x;                 // 0..3
  int mg = blockIdx.y;
  int tl = mg >> 3;
  int mt = ((mg & 7) << 2) + wv;
  const signed char* Arow =
      h1sc + ((size_t)tl * 1024 + mt * 32 + (lane & 31)) * 1024 + ((lane >> 5) << 4);
  const i32x4* Bp = (const i32x4*)Bf + lane;
  const int s0 = wv, s1 = wv + 4;
  const bool has2 = (wv < 2);
#define B2_IDX(s, kc) ((size_t)(((s) * 4 + nt) * 32 + (kc)) * 64)

  i32x16 C[6];
#pragma unroll
  for (int s = 0; s < 6; ++s)
#pragma unroll
    for (int i = 0; i < 16; ++i) C[s][i] = 0;

  i32x4 sa = Bp[B2_IDX(s0, 0)];
  i32x4 sb; if (has2) sb = Bp[B2_IDX(s1, 0)];
  i32x4 a0 = *(const i32x4*)(Arow);
  i32x4 a1 = *(const i32x4*)(Arow + 32);
  i32x4 a2;
  bls[0][s0][lane] = sa;
  if (has2) bls[0][s1][lane] = sb;
  sa = Bp[B2_IDX(s0, 1)];
  if (has2) sb = Bp[B2_IDX(s1, 1)];
  __syncthreads();

  for (int kc = 0; kc < 32; ++kc) {
    const int cur = kc & 1, nxt = cur ^ 1;
    if (kc + 1 < 32) {
      bls[nxt][s0][lane] = sa;
      if (has2) bls[nxt][s1][lane] = sb;
    }
    if (kc + 2 < 32) {
      sa = Bp[B2_IDX(s0, kc + 2)];
      if (has2) sb = Bp[B2_IDX(s1, kc + 2)];
      a2 = *(const i32x4*)(Arow + (size_t)(kc + 2) * 32);
    }
    i32x4 b0 = bls[cur][0][lane], b1 = bls[cur][1][lane], b2 = bls[cur][2][lane];
    i32x4 b3 = bls[cur][3][lane], b4 = bls[cur][4][lane], b5 = bls[cur][5][lane];
    C[0] = __builtin_amdgcn_mfma_i32_32x32x32_i8(a0, b0, C[0], 0, 0, 0);
    C[1] = __builtin_amdgcn_mfma_i32_32x32x32_i8(a0, b1, C[1], 0, 0, 0);
    C[2] = __builtin_amdgcn_mfma_i32_32x32x32_i8(a0, b2, C[2], 0, 0, 0);
    C[3] = __builtin_amdgcn_mfma_i32_32x32x32_i8(a0, b3, C[3], 0, 0, 0);
    C[4] = __builtin_amdgcn_mfma_i32_32x32x32_i8(a0, b4, C[4], 0, 0, 0);
    C[5] = __builtin_amdgcn_mfma_i32_32x32x32_i8(a0, b5, C[5], 0, 0, 0);
    a0 = a1; a1 = a2;
    __syncthreads();
  }

  int o = nt * 32 + (lane & 31);
  int rb = 4 * (lane >> 5);
#pragma unroll
  for (int r = 0; r < 16; ++r) {
    int row = (r & 3) + 8 * (r >> 2) + rb;
    int b = mt * 32 + row;
    long long T = (long long)C[5][r];
    T = (T << 8) + (long long)C[4][r];
    T = (T << 8) + (long long)C[3][r];
    T = (T << 8) + (long long)C[2][r];
    T = (T << 8) + (long long)C[1][r];
    T = (T << 8) + (long long)C[0][r];
    T2[((size_t)tl * 1024 + b) * 128 + o] = (double)T * 0x1p-48;
  }
}

// ---------------------------------------------------------------------------
// rec2: layer-2 membrane recurrence + AvgPool(10) + pPLI accumulator.
// Block = 2 batch rows x 128 outputs; membranes/acc in registers.
// ---------------------------------------------------------------------------
__global__ __launch_bounds__(256) void rec2_kernel(
    const double* __restrict__ T2, double* __restrict__ h2m_st,
    signed char* __restrict__ h2s_st, double* __restrict__ acc_st,
    const float* __restrict__ tauv, const float* __restrict__ acct,
    int t0, int C, float* __restrict__ out) {
  __shared__ signed char sp[256];
  int tid = threadIdx.x;
  int b = blockIdx.x * 2 + (tid >> 7);
  int o = tid & 127;
  double alpha = 1.0 / (1.0 + exp(-(double)tauv[0]));
  double adec  = 1.0 / (1.0 + exp(-(double)acct[0]));
  double m, s, accv = 0.0;
  bool isPool = (o < 10);
  if (t0 == 0) {
    m = 0.5; s = 0.0;
  } else {
    m = h2m_st[(size_t)b * 128 + o];
    s = (double)h2s_st[(size_t)b * 128 + o];
    if (isPool) accv = acc_st[b * 10 + o];
  }
  for (int tl = 0; tl < C; ++tl) {
    double I = T2[((size_t)tl * 1024 + b) * 128 + o];
    m = (s != 0.0 ? 0.0 : m * alpha) + I;
    bool spk = (m - 1.0) >= 0.0;
    s = spk ? 1.0 : 0.0;
    sp[tid] = spk ? 1 : 0;
    __syncthreads();
    if (isPool) {
      int base = tid & 128;
      int isum = 0;
#pragma unroll
      for (int k = 0; k < 10; ++k) isum += sp[base + o * 10 + k];
      accv = accv * adec + (double)isum / 10.0;
      if (t0 + tl == NSTEPS - 1) out[b * 10 + o] = (float)accv;
    }
    __syncthreads();
  }
  h2m_st[(size_t)b * 128 + o] = m;
  h2s_st[(size_t)b * 128 + o] = (signed char)(s != 0.0 ? 1 : 0);
  if (isPool) acc_st[b * 10 + o] = accv;
}

// ---------------------------------------------------------------------------
extern "C" void kernel_launch(void* const* d_in, const int* in_sizes, int n_in,
                              void* d_out, int out_size, void* d_ws, size_t ws_size,
                              hipStream_t stream) {
  const float* x    = (const float*)d_in[0];
  const float* W1   = (const float*)d_in[1];
  const float* W2   = (const float*)d_in[2];
  const float* tau0 = (const float*)d_in[3];
  const float* tauv = (const float*)d_in[4];
  const float* acct = (const float*)d_in[5];
  float* out = (float*)d_out;
  char*  ws  = (char*)d_ws;

  signed char* B1     = (signed char*)(ws + OFF_B1);
  signed char* B2     = (signed char*)(ws + OFF_B2);
  double*      h1m_st = (double*)(ws + OFF_H1MST);
  signed char* h1s_st = (signed char*)(ws + OFF_H1SST);
  double*      h2m_st = (double*)(ws + OFF_H2MST);
  signed char* h2s_st = (signed char*)(ws + OFF_H2SST);
  double*      acc_st = (double*)(ws + OFF_ACCST);
  signed char* Af     = (signed char*)(ws + OFF_AF);

  // adaptive chunking, capped at 13 to keep the chunk working set LLC-resident
  long long avail = (long long)ws_size - (long long)FIXED_END;
  int C = (int)(avail / (long long)PERSTEP);
  if (C < 1) C = 1;
  if (C > 13) C = 13;
  size_t off_t1   = FIXED_END;
  size_t off_h1sc = off_t1 + (size_t)C * 8388608ull;
  size_t off_t2   = off_h1sc + (size_t)C * 1048576ull;
  double*      T1   = (double*)(ws + off_t1);
  signed char* h1sc = (signed char*)(ws + off_h1sc);
  double*      T2   = (double*)(ws + off_t2);

  prep_kernel<<<(6 * 32 * 26 * 1024 + 6 * 4 * 32 * 1024 + 255) / 256, 256, 0, stream>>>(
      W1, W2, B1, B2);
  spikegen_kernel<<<NSTEPS * 32 * 25 / 4, 256, 0, stream>>>(x, (i32x4*)Af);

  for (int t0 = 0; t0 < NSTEPS; t0 += C) {
    int Cc = (NSTEPS - t0 < C) ? (NSTEPS - t0) : C;
    gemm1_kernel<<<dim3(32, Cc * 4), 256, 0, stream>>>(
        B1, Af + (size_t)t0 * 851968ull, T1);
    rec1_kernel<<<512, 256, 0, stream>>>(T1, h1sc, h1m_st, h1s_st, tau0, t0, Cc);
    gemm2_kernel<<<dim3(4, Cc * 8), 256, 0, stream>>>(B2, h1sc, T2);
    rec2_kernel<<<512, 256, 0, stream>>>(T2, h2m_st, h2s_st, acc_st,
                                         tauv, acct, t0, Cc, out);
  }
}